// Round 8
// baseline (397.424 us; speedup 1.0000x reference)
//
#include <hip/hip_runtime.h>
#include <hip/hip_bf16.h>

typedef unsigned short u16;
typedef __attribute__((ext_vector_type(16))) float f32x16;
typedef __attribute__((ext_vector_type(8))) short bf16x8;
typedef __attribute__((ext_vector_type(8))) u16 u16x8;

#define GLDS16(g, l) __builtin_amdgcn_global_load_lds( \
    (const __attribute__((address_space(1))) void*)(g), \
    (__attribute__((address_space(3))) void*)(l), 16, 0, 0)

__device__ inline u16 f2bf(float f) {
  union { float f; unsigned u; } v; v.f = f;
  unsigned r = v.u + 0x7fffu + ((v.u >> 16) & 1u);
  return (u16)(r >> 16);
}

// ---------------------------------------------------------------------------
// Kernel 1 (fused prep): blocks [0,2048) dequant+LoRA -> W bf16;
//                        blocks [2048,4096) x f32 -> bf16.
// Both paths identical to the round-1..7 proven kernels, re-indexed.
// ---------------------------------------------------------------------------
__global__ __launch_bounds__(256) void k_prep(
    const int* __restrict__ qw, const float* __restrict__ sc,
    const float* __restrict__ la, const float* __restrict__ lb,
    const float* __restrict__ x,
    u16* __restrict__ W, u16* __restrict__ xb)
{
  const int I = 4096, R = 16;
  const int tid = threadIdx.x;
  const int b = blockIdx.x;

  if (b < 2048) {
    // ---- dequant + LoRA: 16 rows x 512 cols per block ----
    __shared__ float lbs[16][512];
    __shared__ float las[256];
    const int c0 = (b & 7) * 512;
    const int o0 = (b >> 3) * 16;

    las[tid] = la[(size_t)(o0 + (tid >> 4)) * R + (tid & 15)];
    #pragma unroll
    for (int i = 0; i < 8; ++i) {
      int idx = tid + i * 256;
      int r = idx >> 7;
      int cc4 = (idx & 127) << 2;
      *(float4*)&lbs[r][cc4] = *(const float4*)&lb[(size_t)r * I + c0 + cc4];
    }
    __syncthreads();

    const int cc = (tid & 63) * 8;
    const int rg = tid >> 6;
    #pragma unroll
    for (int rr = 0; rr < 4; ++rr) {
      const int o = o0 + rg * 4 + rr;
      float acc[8] = {0.f,0.f,0.f,0.f,0.f,0.f,0.f,0.f};
      #pragma unroll
      for (int r = 0; r < 16; ++r) {
        float av = las[(rg * 4 + rr) * 16 + r];
        float4 b0 = *(const float4*)&lbs[r][cc];
        float4 b1 = *(const float4*)&lbs[r][cc + 4];
        acc[0] += av * b0.x; acc[1] += av * b0.y;
        acc[2] += av * b0.z; acc[3] += av * b0.w;
        acc[4] += av * b1.x; acc[5] += av * b1.y;
        acc[6] += av * b1.z; acc[7] += av * b1.w;
      }
      const int4* qp = (const int4*)&qw[(size_t)o * I + c0 + cc];
      int4 q0 = qp[0], q1 = qp[1];
      float s = sc[(size_t)o * (I / 32) + ((c0 + cc) >> 5)];
      u16x8 w;
      w[0] = f2bf(((float)q0.x - 8.0f) * s + acc[0]);
      w[1] = f2bf(((float)q0.y - 8.0f) * s + acc[1]);
      w[2] = f2bf(((float)q0.z - 8.0f) * s + acc[2]);
      w[3] = f2bf(((float)q0.w - 8.0f) * s + acc[3]);
      w[4] = f2bf(((float)q1.x - 8.0f) * s + acc[4]);
      w[5] = f2bf(((float)q1.y - 8.0f) * s + acc[5]);
      w[6] = f2bf(((float)q1.z - 8.0f) * s + acc[6]);
      w[7] = f2bf(((float)q1.w - 8.0f) * s + acc[7]);
      *(u16x8*)&W[(size_t)o * I + c0 + cc] = w;
    }
  } else {
    // ---- x f32 -> bf16, grid-stride over 2048 effective blocks ----
    const size_t n = (size_t)8192 * 4096;
    const size_t stride = (size_t)2048 * 256 * 8;
    for (size_t i = ((size_t)(b - 2048) * 256 + tid) * 8; i < n; i += stride) {
      float4 a = *(const float4*)&x[i];
      float4 c = *(const float4*)&x[i + 4];
      u16x8 o;
      o[0] = f2bf(a.x); o[1] = f2bf(a.y); o[2] = f2bf(a.z); o[3] = f2bf(a.w);
      o[4] = f2bf(c.x); o[5] = f2bf(c.y); o[6] = f2bf(c.z); o[7] = f2bf(c.w);
      *(u16x8*)&xb[i] = o;
    }
  }
}

// ---------------------------------------------------------------------------
// Kernel 2: C[M,N] = A[M,K] @ B[N,K]^T + bias
// Round-8: round-7 structure (32x32x16 MFMA, pipelined, 1 barrier/tile,
// counted vmcnt(4)) with CORRECTED swizzle for the 32x32 read pattern:
//   store: LDS[row][chunk p] = global[row][chunk p ^ ((row>>1)&3)]
//          (via pre-swizzled global source, linear gload_lds dest)
//   read:  chunk = (2ks+g) ^ ((row>>1)&3)
// -> each 32-lane phase hits all 8 bank-quads uniformly (old row&8-only
//    swizzle left each half-wave on 4 quads = 2-way conflict = the 2.5e7).
// ---------------------------------------------------------------------------
__global__ __launch_bounds__(512, 1) void k_gemm(
    const u16* __restrict__ A, const u16* __restrict__ B,
    const float* __restrict__ bias, float* __restrict__ C)
{
  const int N = 4096, K = 4096;
  const int NTK = 128;                 // K / 32
  __shared__ u16 As[4 * 8192];         // 4 ring buffers x [256 rows][32 k]
  __shared__ u16 Bs[4 * 8192];

  // XCD swizzle: 512 blocks = 8 XCDs x 64
  const int bid = blockIdx.x;
  const int swz = (bid & 7) * 64 + (bid >> 3);
  const int m0 = (swz >> 4) * 256;     // 32 M-tiles
  const int n0 = (swz & 15) * 256;     // 16 N-tiles

  const int tid = threadIdx.x;
  const int wid = tid >> 6, lane = tid & 63;
  const int wid_m = wid >> 2, wid_n = wid & 3;

  // staging: lane l writes LDS row r=l>>2, chunk (l&3); source must be
  // global chunk (l&3) ^ ((r>>1)&3) = (l&3) ^ ((l>>3)&3)
  const int st0 = wid;
  const int st1 = 8 + wid;
  const int srow = lane >> 2;
  const int schunk = ((lane & 3) ^ ((lane >> 3) & 3)) * 8;
  const u16* Asrc0 = A + (size_t)(m0 + st0 * 16 + srow) * K + schunk;
  const u16* Asrc1 = A + (size_t)(m0 + st1 * 16 + srow) * K + schunk;
  const u16* Bsrc0 = B + (size_t)(n0 + st0 * 16 + srow) * K + schunk;
  const u16* Bsrc1 = B + (size_t)(n0 + st1 * 16 + srow) * K + schunk;

#define STAGE_A(buf, t) do { \
    GLDS16(Asrc0 + (size_t)(t) * 32, &As[(buf) * 8192 + st0 * 512]); \
    GLDS16(Asrc1 + (size_t)(t) * 32, &As[(buf) * 8192 + st1 * 512]); } while (0)
#define STAGE_B(buf, t) do { \
    GLDS16(Bsrc0 + (size_t)(t) * 32, &Bs[(buf) * 8192 + st0 * 512]); \
    GLDS16(Bsrc1 + (size_t)(t) * 32, &Bs[(buf) * 8192 + st1 * 512]); } while (0)

  // 32x32 frag read: row = base + (lane&31), k = ks*16 + (lane>>5)*8
  // elem = ((lane>>4)&1)*512 + (lane&15)*32
  //        + (((lane>>5) ^ ((lane>>1)&3)) * 8   [ks via ^ (ks<<4)]
  const int LA = ((lane >> 4) & 1) * 512 + (lane & 15) * 32 +
                 (((lane >> 5) ^ ((lane >> 1) & 3)) * 8);
  const int wmb = wid_m * 8;           // A base subtile
  const int wnb = wid_n * 4;           // B base subtile

  f32x16 acc[4][2] = {};               // [mi][ni], 128 f32/lane
  bf16x8 aC[4], aN[4], bA[4], bB[4];   // frag double-buffers [mi*2+ks]/[ni*2+ks]

  // ---- prologue: stage tiles 0,1; wait tile 0; read tile-0 frags ----
  STAGE_A(0, 0); STAGE_B(0, 0);
  STAGE_A(1, 1); STAGE_B(1, 1);
  asm volatile("s_waitcnt vmcnt(4)" ::: "memory");   // tile 0 landed
  __builtin_amdgcn_s_barrier();
  __builtin_amdgcn_sched_barrier(0);
  #pragma unroll
  for (int mi = 0; mi < 2; ++mi)
    #pragma unroll
    for (int ks = 0; ks < 2; ++ks)
      aC[mi * 2 + ks] = *(const bf16x8*)&As[(wmb + mi * 2) * 512 + (LA ^ (ks << 4))];
  #pragma unroll
  for (int ni = 0; ni < 2; ++ni)
    #pragma unroll
    for (int ks = 0; ks < 2; ++ks)
      bA[ni * 2 + ks] = *(const bf16x8*)&Bs[(wnb + ni * 2) * 512 + (LA ^ (ks << 4))];

#define TILE(T, BCUR, BNXT) do { \
    const int b_ = (T) & 3; \
    const int bn_ = ((T) + 1) & 3; \
    _Pragma("unroll") \
    for (int mi = 0; mi < 2; ++mi) { \
      _Pragma("unroll") \
      for (int ks = 0; ks < 2; ++ks) \
        aN[mi * 2 + ks] = *(const bf16x8*)&As[b_ * 8192 + (wmb + 4 + mi * 2) * 512 + (LA ^ (ks << 4))]; \
    } \
    if ((T) + 2 < NTK) STAGE_A(((T) + 2) & 3, (T) + 2); \
    __builtin_amdgcn_s_setprio(1); \
    _Pragma("unroll") \
    for (int ks = 0; ks < 2; ++ks) { \
      _Pragma("unroll") \
      for (int mi = 0; mi < 2; ++mi) { \
        _Pragma("unroll") \
        for (int ni = 0; ni < 2; ++ni) \
          acc[mi][ni] = __builtin_amdgcn_mfma_f32_32x32x16_bf16(aC[mi * 2 + ks], BCUR[ni * 2 + ks], acc[mi][ni], 0, 0, 0); \
      } \
    } \
    __builtin_amdgcn_s_setprio(0); \
    if ((T) + 2 < NTK) { \
      STAGE_B(((T) + 2) & 3, (T) + 2); \
      asm volatile("s_waitcnt vmcnt(4)" ::: "memory"); \
    } else { \
      asm volatile("s_waitcnt vmcnt(0)" ::: "memory"); \
    } \
    __builtin_amdgcn_sched_barrier(0); \
    __builtin_amdgcn_s_barrier(); \
    __builtin_amdgcn_sched_barrier(0); \
    if ((T) + 1 < NTK) { \
      _Pragma("unroll") \
      for (int mi = 0; mi < 2; ++mi) { \
        _Pragma("unroll") \
        for (int ks = 0; ks < 2; ++ks) \
          aC[mi * 2 + ks] = *(const bf16x8*)&As[bn_ * 8192 + (wmb + mi * 2) * 512 + (LA ^ (ks << 4))]; \
      } \
      _Pragma("unroll") \
      for (int ni = 0; ni < 2; ++ni) { \
        _Pragma("unroll") \
        for (int ks = 0; ks < 2; ++ks) \
          BNXT[ni * 2 + ks] = *(const bf16x8*)&Bs[bn_ * 8192 + (wnb + ni * 2) * 512 + (LA ^ (ks << 4))]; \
      } \
    } \
    __builtin_amdgcn_s_setprio(1); \
    _Pragma("unroll") \
    for (int ks = 0; ks < 2; ++ks) { \
      _Pragma("unroll") \
      for (int mi = 0; mi < 2; ++mi) { \
        _Pragma("unroll") \
        for (int ni = 0; ni < 2; ++ni) \
          acc[2 + mi][ni] = __builtin_amdgcn_mfma_f32_32x32x16_bf16(aN[mi * 2 + ks], BCUR[ni * 2 + ks], acc[2 + mi][ni], 0, 0, 0); \
      } \
    } \
    __builtin_amdgcn_s_setprio(0); \
  } while (0)

  for (int t = 0; t < NTK; t += 2) {
    TILE(t, bA, bB);
    TILE(t + 1, bB, bA);
  }
#undef TILE
#undef STAGE_A
#undef STAGE_B

  // ---- epilogue: 32x32 C/D layout col=lane&31, row=(reg&3)+8*(reg>>2)+4*(lane>>5)
  const int crow0 = m0 + wid_m * 128 + ((lane >> 5) << 2);
  const int ccol = n0 + wid_n * 64 + (lane & 31);
  #pragma unroll
  for (int ni = 0; ni < 2; ++ni) {
    float bv = bias[ccol + ni * 32];
    #pragma unroll
    for (int mi = 0; mi < 4; ++mi) {
      #pragma unroll
      for (int reg = 0; reg < 16; ++reg) {
        int row = crow0 + mi * 32 + (reg & 3) + ((reg >> 2) << 3);
        C[(size_t)row * N + ccol + ni * 32] = acc[mi][ni][reg] + bv;
      }
    }
  }
}

// ---------------------------------------------------------------------------
extern "C" void kernel_launch(void* const* d_in, const int* in_sizes, int n_in,
                              void* d_out, int out_size, void* d_ws, size_t ws_size,
                              hipStream_t stream) {
  const float* x    = (const float*)d_in[0];   // [8192, 4096] f32
  const int*   qw   = (const int*)d_in[1];     // [4096, 4096] i32
  const float* sc   = (const float*)d_in[2];   // [4096, 128]  f32
  const float* la   = (const float*)d_in[3];   // [4096, 16]   f32
  const float* lb   = (const float*)d_in[4];   // [16, 4096]   f32
  const float* bias = (const float*)d_in[5];   // [4096]       f32
  float* y = (float*)d_out;                    // [8192, 4096] f32

  u16* W  = (u16*)d_ws;                                        // 32 MiB
  u16* Xb = (u16*)((char*)d_ws + (size_t)32 * 1024 * 1024);    // 64 MiB

  k_prep<<<4096, 256, 0, stream>>>(qw, sc, la, lb, x, W, Xb);
  const int ngemm = (8192 / 256) * (4096 / 256);   // 512
  k_gemm<<<ngemm, 512, 0, stream>>>(Xb, W, bias, y);
}

// Round 9
// 389.499 us; speedup vs baseline: 1.0203x; 1.0203x over previous
//
#include <hip/hip_runtime.h>
#include <hip/hip_bf16.h>

typedef unsigned short u16;
typedef __attribute__((ext_vector_type(16))) float f32x16;
typedef __attribute__((ext_vector_type(8))) short bf16x8;
typedef __attribute__((ext_vector_type(8))) u16 u16x8;

#define GLDS16(g, l) __builtin_amdgcn_global_load_lds( \
    (const __attribute__((address_space(1))) void*)(g), \
    (__attribute__((address_space(3))) void*)(l), 16, 0, 0)

__device__ inline u16 f2bf(float f) {
  union { float f; unsigned u; } v; v.f = f;
  unsigned r = v.u + 0x7fffu + ((v.u >> 16) & 1u);
  return (u16)(r >> 16);
}

// ---------------------------------------------------------------------------
// Kernel 1: W[o][i] = (q[o][i]-8)*scale[o][i/32] + sum_r la[o][r]*lb[r][i]
// (separate launch — round-8 fusion measured -15us; reverted)
// ---------------------------------------------------------------------------
__global__ __launch_bounds__(256) void k_dequant_lora(
    const int* __restrict__ qw, const float* __restrict__ sc,
    const float* __restrict__ la, const float* __restrict__ lb,
    u16* __restrict__ W)
{
  const int I = 4096, R = 16;
  __shared__ float lbs[16][512];
  __shared__ float las[256];
  const int c0 = blockIdx.x * 512;
  const int o0 = blockIdx.y * 16;
  const int tid = threadIdx.x;

  las[tid] = la[(size_t)(o0 + (tid >> 4)) * R + (tid & 15)];
  #pragma unroll
  for (int i = 0; i < 8; ++i) {
    int idx = tid + i * 256;
    int r = idx >> 7;
    int cc4 = (idx & 127) << 2;
    *(float4*)&lbs[r][cc4] = *(const float4*)&lb[(size_t)r * I + c0 + cc4];
  }
  __syncthreads();

  const int cc = (tid & 63) * 8;
  const int rg = tid >> 6;
  #pragma unroll
  for (int rr = 0; rr < 4; ++rr) {
    const int o = o0 + rg * 4 + rr;
    float acc[8] = {0.f,0.f,0.f,0.f,0.f,0.f,0.f,0.f};
    #pragma unroll
    for (int r = 0; r < 16; ++r) {
      float av = las[(rg * 4 + rr) * 16 + r];
      float4 b0 = *(const float4*)&lbs[r][cc];
      float4 b1 = *(const float4*)&lbs[r][cc + 4];
      acc[0] += av * b0.x; acc[1] += av * b0.y;
      acc[2] += av * b0.z; acc[3] += av * b0.w;
      acc[4] += av * b1.x; acc[5] += av * b1.y;
      acc[6] += av * b1.z; acc[7] += av * b1.w;
    }
    const int4* qp = (const int4*)&qw[(size_t)o * I + c0 + cc];
    int4 q0 = qp[0], q1 = qp[1];
    float s = sc[(size_t)o * (I / 32) + ((c0 + cc) >> 5)];
    u16x8 w;
    w[0] = f2bf(((float)q0.x - 8.0f) * s + acc[0]);
    w[1] = f2bf(((float)q0.y - 8.0f) * s + acc[1]);
    w[2] = f2bf(((float)q0.z - 8.0f) * s + acc[2]);
    w[3] = f2bf(((float)q0.w - 8.0f) * s + acc[3]);
    w[4] = f2bf(((float)q1.x - 8.0f) * s + acc[4]);
    w[5] = f2bf(((float)q1.y - 8.0f) * s + acc[5]);
    w[6] = f2bf(((float)q1.z - 8.0f) * s + acc[6]);
    w[7] = f2bf(((float)q1.w - 8.0f) * s + acc[7]);
    *(u16x8*)&W[(size_t)o * I + c0 + cc] = w;
  }
}

// ---------------------------------------------------------------------------
// Kernel 2: x (f32) -> bf16
// ---------------------------------------------------------------------------
__global__ __launch_bounds__(256) void k_cvt(const float* __restrict__ x,
                                             u16* __restrict__ xb)
{
  const size_t n = (size_t)8192 * 4096;
  const size_t stride = (size_t)gridDim.x * 256 * 8;
  for (size_t i = ((size_t)blockIdx.x * 256 + threadIdx.x) * 8; i < n; i += stride) {
    float4 a = *(const float4*)&x[i];
    float4 b = *(const float4*)&x[i + 4];
    u16x8 o;
    o[0] = f2bf(a.x); o[1] = f2bf(a.y); o[2] = f2bf(a.z); o[3] = f2bf(a.w);
    o[4] = f2bf(b.x); o[5] = f2bf(b.y); o[6] = f2bf(b.z); o[7] = f2bf(b.w);
    *(u16x8*)&xb[i] = o;
  }
}

// ---------------------------------------------------------------------------
// Kernel 3: C[M,N] = A[M,K] @ B[N,K]^T + bias
// Round-9: 32x32x16 MFMA + PANEL LDS LAYOUT so each ds_read_b128 is one
// dense 1024B window. Conflict model H (fits all rounds 2-8 data): b128
// reads spanning two 1024B windows pay one extra 4-beat pass
// (2.517e7 = 512blk x 128tile x 96reads x 4cyc, exact). Panel layout:
//   phys = ks*4096 + row*16 + (kc&1)*8 + (k&7)   [per 8KB ring buffer]
// Read (frag R0, ks): elem = ks*4096 + (R0+(lane&31))*16 + (lane>>5)*8
//   -> contiguous [base, base+512 elems), window-aligned (R0 mult of 32).
// Staging: window (ks, wid) = rows [32wid,32wid+32) x chunks {2ks,2ks+1};
// lane l fetches global row 32wid+(l>>1), chunk 2ks+(l&1) (32B pairs),
// linear gload_lds dest. Pipelined skeleton identical to round 3/7/8.
// ---------------------------------------------------------------------------
__global__ __launch_bounds__(512, 1) void k_gemm(
    const u16* __restrict__ A, const u16* __restrict__ B,
    const float* __restrict__ bias, float* __restrict__ C)
{
  const int N = 4096, K = 4096;
  const int NTK = 128;                 // K / 32
  __shared__ u16 As[4 * 8192];         // 4 ring buffers, panel layout
  __shared__ u16 Bs[4 * 8192];

  // XCD swizzle: 512 blocks = 8 XCDs x 64
  const int bid = blockIdx.x;
  const int swz = (bid & 7) * 64 + (bid >> 3);
  const int m0 = (swz >> 4) * 256;     // 32 M-tiles
  const int n0 = (swz & 15) * 256;     // 16 N-tiles

  const int tid = threadIdx.x;
  const int wid = tid >> 6, lane = tid & 63;
  const int wid_m = wid >> 2, wid_n = wid & 3;

  // staging: window st0=(ks0,wid) rows [32wid,+32) chunks {0,1};
  //          window st1=(ks1,wid) same rows chunks {2,3}
  const int srow = 32 * wid + (lane >> 1);
  const int seo  = (lane & 1) * 8;
  const u16* Asrc0 = A + (size_t)(m0 + srow) * K + seo;        // ks=0
  const u16* Asrc1 = A + (size_t)(m0 + srow) * K + 16 + seo;   // ks=1
  const u16* Bsrc0 = B + (size_t)(n0 + srow) * K + seo;
  const u16* Bsrc1 = B + (size_t)(n0 + srow) * K + 16 + seo;

#define STAGE_A(buf, t) do { \
    GLDS16(Asrc0 + (size_t)(t) * 32, &As[(buf) * 8192 + wid * 512]); \
    GLDS16(Asrc1 + (size_t)(t) * 32, &As[(buf) * 8192 + 4096 + wid * 512]); } while (0)
#define STAGE_B(buf, t) do { \
    GLDS16(Bsrc0 + (size_t)(t) * 32, &Bs[(buf) * 8192 + wid * 512]); \
    GLDS16(Bsrc1 + (size_t)(t) * 32, &Bs[(buf) * 8192 + 4096 + wid * 512]); } while (0)

  // fragment read: one dense 1KB window per instruction
  const int LA  = (lane & 31) * 16 + (lane >> 5) * 8;
  const int wmA = wid_m * 2048;        // A row-block base (elems): rows wid_m*128
  const int wnB = wid_n * 1024;        // B row-block base: rows wid_n*64

  f32x16 acc[4][2] = {};               // [mi][ni], 128 f32/lane
  bf16x8 aC[4], aN[4], bA[4], bB[4];   // frag double-buffers [mi*2+ks]/[ni*2+ks]

  // ---- prologue: stage tiles 0,1; wait tile 0; read tile-0 frags ----
  STAGE_A(0, 0); STAGE_B(0, 0);
  STAGE_A(1, 1); STAGE_B(1, 1);
  asm volatile("s_waitcnt vmcnt(4)" ::: "memory");   // tile 0 landed
  __builtin_amdgcn_s_barrier();
  __builtin_amdgcn_sched_barrier(0);
  #pragma unroll
  for (int mi = 0; mi < 2; ++mi)
    #pragma unroll
    for (int ks = 0; ks < 2; ++ks)
      aC[mi * 2 + ks] = *(const bf16x8*)&As[ks * 4096 + wmA + mi * 512 + LA];
  #pragma unroll
  for (int ni = 0; ni < 2; ++ni)
    #pragma unroll
    for (int ks = 0; ks < 2; ++ks)
      bA[ni * 2 + ks] = *(const bf16x8*)&Bs[ks * 4096 + wnB + ni * 512 + LA];

#define TILE(T, BCUR, BNXT) do { \
    const int b_ = (T) & 3; \
    const int bn_ = ((T) + 1) & 3; \
    _Pragma("unroll") \
    for (int mi = 0; mi < 2; ++mi) { \
      _Pragma("unroll") \
      for (int ks = 0; ks < 2; ++ks) \
        aN[mi * 2 + ks] = *(const bf16x8*)&As[b_ * 8192 + ks * 4096 + wmA + (2 + mi) * 512 + LA]; \
    } \
    if ((T) + 2 < NTK) STAGE_A(((T) + 2) & 3, (T) + 2); \
    __builtin_amdgcn_s_setprio(1); \
    _Pragma("unroll") \
    for (int ks = 0; ks < 2; ++ks) { \
      _Pragma("unroll") \
      for (int mi = 0; mi < 2; ++mi) { \
        _Pragma("unroll") \
        for (int ni = 0; ni < 2; ++ni) \
          acc[mi][ni] = __builtin_amdgcn_mfma_f32_32x32x16_bf16(aC[mi * 2 + ks], BCUR[ni * 2 + ks], acc[mi][ni], 0, 0, 0); \
      } \
    } \
    __builtin_amdgcn_s_setprio(0); \
    if ((T) + 2 < NTK) { \
      STAGE_B(((T) + 2) & 3, (T) + 2); \
      asm volatile("s_waitcnt vmcnt(4)" ::: "memory"); \
    } else { \
      asm volatile("s_waitcnt vmcnt(0)" ::: "memory"); \
    } \
    __builtin_amdgcn_sched_barrier(0); \
    __builtin_amdgcn_s_barrier(); \
    __builtin_amdgcn_sched_barrier(0); \
    if ((T) + 1 < NTK) { \
      _Pragma("unroll") \
      for (int mi = 0; mi < 2; ++mi) { \
        _Pragma("unroll") \
        for (int ks = 0; ks < 2; ++ks) \
          aC[mi * 2 + ks] = *(const bf16x8*)&As[bn_ * 8192 + ks * 4096 + wmA + mi * 512 + LA]; \
      } \
      _Pragma("unroll") \
      for (int ni = 0; ni < 2; ++ni) { \
        _Pragma("unroll") \
        for (int ks = 0; ks < 2; ++ks) \
          BNXT[ni * 2 + ks] = *(const bf16x8*)&Bs[bn_ * 8192 + ks * 4096 + wnB + ni * 512 + LA]; \
      } \
    } \
    __builtin_amdgcn_s_setprio(1); \
    _Pragma("unroll") \
    for (int ks = 0; ks < 2; ++ks) { \
      _Pragma("unroll") \
      for (int mi = 0; mi < 2; ++mi) { \
        _Pragma("unroll") \
        for (int ni = 0; ni < 2; ++ni) \
          acc[2 + mi][ni] = __builtin_amdgcn_mfma_f32_32x32x16_bf16(aN[mi * 2 + ks], BCUR[ni * 2 + ks], acc[2 + mi][ni], 0, 0, 0); \
      } \
    } \
    __builtin_amdgcn_s_setprio(0); \
  } while (0)

  for (int t = 0; t < NTK; t += 2) {
    TILE(t, bA, bB);
    TILE(t + 1, bB, bA);
  }
#undef TILE
#undef STAGE_A
#undef STAGE_B

  // ---- epilogue: 32x32 C/D layout col=lane&31, row=(reg&3)+8*(reg>>2)+4*(lane>>5)
  const int crow0 = m0 + wid_m * 128 + ((lane >> 5) << 2);
  const int ccol = n0 + wid_n * 64 + (lane & 31);
  #pragma unroll
  for (int ni = 0; ni < 2; ++ni) {
    float bv = bias[ccol + ni * 32];
    #pragma unroll
    for (int mi = 0; mi < 4; ++mi) {
      #pragma unroll
      for (int reg = 0; reg < 16; ++reg) {
        int row = crow0 + mi * 32 + (reg & 3) + ((reg >> 2) << 3);
        C[(size_t)row * N + ccol + ni * 32] = acc[mi][ni][reg] + bv;
      }
    }
  }
}

// ---------------------------------------------------------------------------
extern "C" void kernel_launch(void* const* d_in, const int* in_sizes, int n_in,
                              void* d_out, int out_size, void* d_ws, size_t ws_size,
                              hipStream_t stream) {
  const float* x    = (const float*)d_in[0];   // [8192, 4096] f32
  const int*   qw   = (const int*)d_in[1];     // [4096, 4096] i32
  const float* sc   = (const float*)d_in[2];   // [4096, 128]  f32
  const float* la   = (const float*)d_in[3];   // [4096, 16]   f32
  const float* lb   = (const float*)d_in[4];   // [16, 4096]   f32
  const float* bias = (const float*)d_in[5];   // [4096]       f32
  float* y = (float*)d_out;                    // [8192, 4096] f32

  u16* W  = (u16*)d_ws;                                        // 32 MiB
  u16* Xb = (u16*)((char*)d_ws + (size_t)32 * 1024 * 1024);    // 64 MiB

  dim3 gridD(4096 / 512, 4096 / 16);
  k_dequant_lora<<<gridD, 256, 0, stream>>>(qw, sc, la, lb, W);
  k_cvt<<<2048, 256, 0, stream>>>(x, Xb);
  const int ngemm = (8192 / 256) * (4096 / 256);   // 512
  k_gemm<<<ngemm, 512, 0, stream>>>(Xb, W, bias, y);
}

// Round 10
// 356.651 us; speedup vs baseline: 1.1143x; 1.0921x over previous
//
#include <hip/hip_runtime.h>
#include <hip/hip_bf16.h>

typedef unsigned short u16;
typedef __attribute__((ext_vector_type(4))) float f32x4;
typedef __attribute__((ext_vector_type(8))) short bf16x8;
typedef __attribute__((ext_vector_type(8))) u16 u16x8;

#define GLDS16(g, l) __builtin_amdgcn_global_load_lds( \
    (const __attribute__((address_space(1))) void*)(g), \
    (__attribute__((address_space(3))) void*)(l), 16, 0, 0)

__device__ inline u16 f2bf(float f) {
  union { float f; unsigned u; } v; v.f = f;
  unsigned r = v.u + 0x7fffu + ((v.u >> 16) & 1u);
  return (u16)(r >> 16);
}

// ---------------------------------------------------------------------------
// Kernel 1: W[o][i] = (q[o][i]-8)*scale[o][i/32] + sum_r la[o][r]*lb[r][i]
// ---------------------------------------------------------------------------
__global__ __launch_bounds__(256) void k_dequant_lora(
    const int* __restrict__ qw, const float* __restrict__ sc,
    const float* __restrict__ la, const float* __restrict__ lb,
    u16* __restrict__ W)
{
  const int I = 4096, R = 16;
  __shared__ float lbs[16][512];
  __shared__ float las[256];
  const int c0 = blockIdx.x * 512;
  const int o0 = blockIdx.y * 16;
  const int tid = threadIdx.x;

  las[tid] = la[(size_t)(o0 + (tid >> 4)) * R + (tid & 15)];
  #pragma unroll
  for (int i = 0; i < 8; ++i) {
    int idx = tid + i * 256;
    int r = idx >> 7;
    int cc4 = (idx & 127) << 2;
    *(float4*)&lbs[r][cc4] = *(const float4*)&lb[(size_t)r * I + c0 + cc4];
  }
  __syncthreads();

  const int cc = (tid & 63) * 8;
  const int rg = tid >> 6;
  #pragma unroll
  for (int rr = 0; rr < 4; ++rr) {
    const int o = o0 + rg * 4 + rr;
    float acc[8] = {0.f,0.f,0.f,0.f,0.f,0.f,0.f,0.f};
    #pragma unroll
    for (int r = 0; r < 16; ++r) {
      float av = las[(rg * 4 + rr) * 16 + r];
      float4 b0 = *(const float4*)&lbs[r][cc];
      float4 b1 = *(const float4*)&lbs[r][cc + 4];
      acc[0] += av * b0.x; acc[1] += av * b0.y;
      acc[2] += av * b0.z; acc[3] += av * b0.w;
      acc[4] += av * b1.x; acc[5] += av * b1.y;
      acc[6] += av * b1.z; acc[7] += av * b1.w;
    }
    const int4* qp = (const int4*)&qw[(size_t)o * I + c0 + cc];
    int4 q0 = qp[0], q1 = qp[1];
    float s = sc[(size_t)o * (I / 32) + ((c0 + cc) >> 5)];
    u16x8 w;
    w[0] = f2bf(((float)q0.x - 8.0f) * s + acc[0]);
    w[1] = f2bf(((float)q0.y - 8.0f) * s + acc[1]);
    w[2] = f2bf(((float)q0.z - 8.0f) * s + acc[2]);
    w[3] = f2bf(((float)q0.w - 8.0f) * s + acc[3]);
    w[4] = f2bf(((float)q1.x - 8.0f) * s + acc[4]);
    w[5] = f2bf(((float)q1.y - 8.0f) * s + acc[5]);
    w[6] = f2bf(((float)q1.z - 8.0f) * s + acc[6]);
    w[7] = f2bf(((float)q1.w - 8.0f) * s + acc[7]);
    *(u16x8*)&W[(size_t)o * I + c0 + cc] = w;
  }
}

// ---------------------------------------------------------------------------
// Kernel 2: x (f32) -> bf16
// ---------------------------------------------------------------------------
__global__ __launch_bounds__(256) void k_cvt(const float* __restrict__ x,
                                             u16* __restrict__ xb)
{
  const size_t n = (size_t)8192 * 4096;
  const size_t stride = (size_t)gridDim.x * 256 * 8;
  for (size_t i = ((size_t)blockIdx.x * 256 + threadIdx.x) * 8; i < n; i += stride) {
    float4 a = *(const float4*)&x[i];
    float4 b = *(const float4*)&x[i + 4];
    u16x8 o;
    o[0] = f2bf(a.x); o[1] = f2bf(a.y); o[2] = f2bf(a.z); o[3] = f2bf(a.w);
    o[4] = f2bf(b.x); o[5] = f2bf(b.y); o[6] = f2bf(b.z); o[7] = f2bf(b.w);
    *(u16x8*)&xb[i] = o;
  }
}

// ---------------------------------------------------------------------------
// Kernel 3: C[M,N] = A[M,K] @ B[N,K]^T + bias
// Round-10: round-3 base (16x16x32 MFMA, 4-ring BK=32, 0-conflict layout,
// counted vmcnt(4)) with the sync re-phased to BARRIER-ABSORPTION:
// 2 barriers/tile; every ds_read issues exactly ONE barrier before its
// consuming MFMA, and the consumer waits lgkmcnt(0) right after that
// barrier -> read latency is absorbed by the barrier wait (m218/m201
// mechanism) instead of exposed to the MFMA cluster (round-3) or paid
// with 4 barriers/tile (round-4).
//   P1(t): read aN(t,m4-7); stage A(t+2); [SB] bar; lgkm0 [SB];
//          MFMA c1 = aC x bCur   (read in P2(t-1), 1 barrier ago)
//   P2(t): read aC'(t+1,m0-3) + bNxt(t+1); stage B(t+2); vmcnt(4);
//          [SB] bar; lgkm0 [SB];
//          MFMA c2 = aN x bCur   (read in P1(t), 1 barrier ago)
// Race guarantees inherited from round 3: t+1 published via vmcnt(4)+bar;
// WAR on ring buffer separated by >=3 barriers.
// ---------------------------------------------------------------------------
__global__ __launch_bounds__(512, 1) void k_gemm(
    const u16* __restrict__ A, const u16* __restrict__ B,
    const float* __restrict__ bias, float* __restrict__ C)
{
  const int N = 4096, K = 4096;
  const int NTK = 128;                 // K / 32
  __shared__ u16 As[4 * 8192];         // 4 ring buffers x [256 rows][32 k]
  __shared__ u16 Bs[4 * 8192];

  // XCD swizzle: 512 blocks = 8 XCDs x 64
  const int bid = blockIdx.x;
  const int swz = (bid & 7) * 64 + (bid >> 3);
  const int m0 = (swz >> 4) * 256;     // 32 M-tiles
  const int n0 = (swz & 15) * 256;     // 16 N-tiles

  const int tid = threadIdx.x;
  const int wid = tid >> 6, lane = tid & 63;
  const int wid_m = wid >> 2, wid_n = wid & 3;

  // staging geometry (round-3, refcheck-passed, 0 conflicts measured)
  const int st0 = wid;
  const int st1 = 8 + wid;
  const int srow = lane >> 2;
  const int schunk = (((lane & 3) ^ (((lane >> 5) & 1) << 1))) * 8;
  const u16* Asrc0 = A + (size_t)(m0 + st0 * 16 + srow) * K + schunk;
  const u16* Asrc1 = A + (size_t)(m0 + st1 * 16 + srow) * K + schunk;
  const u16* Bsrc0 = B + (size_t)(n0 + st0 * 16 + srow) * K + schunk;
  const u16* Bsrc1 = B + (size_t)(n0 + st1 * 16 + srow) * K + schunk;

#define STAGE_A(buf, t) do { \
    GLDS16(Asrc0 + (size_t)(t) * 32, &As[(buf) * 8192 + st0 * 512]); \
    GLDS16(Asrc1 + (size_t)(t) * 32, &As[(buf) * 8192 + st1 * 512]); } while (0)
#define STAGE_B(buf, t) do { \
    GLDS16(Bsrc0 + (size_t)(t) * 32, &Bs[(buf) * 8192 + st0 * 512]); \
    GLDS16(Bsrc1 + (size_t)(t) * 32, &Bs[(buf) * 8192 + st1 * 512]); } while (0)

  // round-3 fragment read offset (measured 0 bank conflicts)
  const int LA = (lane & 15) * 32 + (((lane >> 4) * 8) ^ ((lane & 8) ? 16 : 0));
  const int wmb = wid_m * 8;           // A frag base (8 m-frags per wave)
  const int wnb = wid_n * 4;           // B frag base (4 n-frags per wave)

  f32x4 acc[8][4] = {};
  bf16x8 aC[4], aN[4], bA[4], bB[4];   // register double-buffers

  // ---- prologue: stage tiles 0,1; publish tile 0; pre-read c1(0) operands
  STAGE_A(0, 0); STAGE_B(0, 0);
  STAGE_A(1, 1); STAGE_B(1, 1);
  asm volatile("s_waitcnt vmcnt(4)" ::: "memory");   // tile 0 landed
  __builtin_amdgcn_s_barrier();
  __builtin_amdgcn_sched_barrier(0);
  #pragma unroll
  for (int m = 0; m < 4; ++m)
    aC[m] = *(const bf16x8*)&As[(wmb + m) * 512 + LA];
  #pragma unroll
  for (int n = 0; n < 4; ++n)
    bA[n] = *(const bf16x8*)&Bs[(wnb + n) * 512 + LA];

#define TILE(T, BCUR, BNXT) do { \
    const int b_ = (T) & 3; \
    const int bn_ = ((T) + 1) & 3; \
    /* ---- P1: read aN(t); stage A(t+2); bar; lgkm0; MFMA c1 ---- */ \
    _Pragma("unroll") \
    for (int m = 0; m < 4; ++m) \
      aN[m] = *(const bf16x8*)&As[b_ * 8192 + (wmb + 4 + m) * 512 + LA]; \
    if ((T) + 2 < NTK) STAGE_A(((T) + 2) & 3, (T) + 2); \
    __builtin_amdgcn_sched_barrier(0); \
    __builtin_amdgcn_s_barrier(); \
    asm volatile("s_waitcnt lgkmcnt(0)" ::: "memory"); \
    __builtin_amdgcn_sched_barrier(0); \
    __builtin_amdgcn_s_setprio(1); \
    _Pragma("unroll") \
    for (int m = 0; m < 4; ++m) { \
      _Pragma("unroll") \
      for (int n = 0; n < 4; ++n) \
        acc[m][n] = __builtin_amdgcn_mfma_f32_16x16x32_bf16(aC[m], BCUR[n], acc[m][n], 0, 0, 0); \
    } \
    __builtin_amdgcn_s_setprio(0); \
    /* ---- P2: read aC'(t+1)+bNxt(t+1); stage B(t+2); vmcnt; bar; lgkm0; c2 */ \
    if ((T) + 1 < NTK) { \
      _Pragma("unroll") \
      for (int m = 0; m < 4; ++m) \
        aC[m] = *(const bf16x8*)&As[bn_ * 8192 + (wmb + m) * 512 + LA]; \
      _Pragma("unroll") \
      for (int n = 0; n < 4; ++n) \
        BNXT[n] = *(const bf16x8*)&Bs[bn_ * 8192 + (wnb + n) * 512 + LA]; \
    } \
    if ((T) + 2 < NTK) { \
      STAGE_B(((T) + 2) & 3, (T) + 2); \
      asm volatile("s_waitcnt vmcnt(4)" ::: "memory"); \
    } else { \
      asm volatile("s_waitcnt vmcnt(0)" ::: "memory"); \
    } \
    __builtin_amdgcn_sched_barrier(0); \
    __builtin_amdgcn_s_barrier(); \
    asm volatile("s_waitcnt lgkmcnt(0)" ::: "memory"); \
    __builtin_amdgcn_sched_barrier(0); \
    __builtin_amdgcn_s_setprio(1); \
    _Pragma("unroll") \
    for (int m = 0; m < 4; ++m) { \
      _Pragma("unroll") \
      for (int n = 0; n < 4; ++n) \
        acc[4 + m][n] = __builtin_amdgcn_mfma_f32_16x16x32_bf16(aN[m], BCUR[n], acc[4 + m][n], 0, 0, 0); \
    } \
    __builtin_amdgcn_s_setprio(0); \
  } while (0)

  for (int t = 0; t < NTK; t += 2) {
    TILE(t, bA, bB);
    TILE(t + 1, bB, bA);
  }
#undef TILE
#undef STAGE_A
#undef STAGE_B

  // ---- epilogue: C/D layout col=lane&15, row=(lane>>4)*4+j ----
  const int crow = m0 + wid_m * 128 + ((lane >> 4) << 2);
  const int ccol = n0 + wid_n * 64 + (lane & 15);
  #pragma unroll
  for (int n = 0; n < 4; ++n) {
    float bv = bias[ccol + n * 16];
    #pragma unroll
    for (int m = 0; m < 8; ++m) {
      #pragma unroll
      for (int j = 0; j < 4; ++j) {
        C[(size_t)(crow + m * 16 + j) * N + ccol + n * 16] = acc[m][n][j] + bv;
      }
    }
  }
}

// ---------------------------------------------------------------------------
extern "C" void kernel_launch(void* const* d_in, const int* in_sizes, int n_in,
                              void* d_out, int out_size, void* d_ws, size_t ws_size,
                              hipStream_t stream) {
  const float* x    = (const float*)d_in[0];   // [8192, 4096] f32
  const int*   qw   = (const int*)d_in[1];     // [4096, 4096] i32
  const float* sc   = (const float*)d_in[2];   // [4096, 128]  f32
  const float* la   = (const float*)d_in[3];   // [4096, 16]   f32
  const float* lb   = (const float*)d_in[4];   // [16, 4096]   f32
  const float* bias = (const float*)d_in[5];   // [4096]       f32
  float* y = (float*)d_out;                    // [8192, 4096] f32

  u16* W  = (u16*)d_ws;                                        // 32 MiB
  u16* Xb = (u16*)((char*)d_ws + (size_t)32 * 1024 * 1024);    // 64 MiB

  dim3 gridD(4096 / 512, 4096 / 16);
  k_dequant_lora<<<gridD, 256, 0, stream>>>(qw, sc, la, lb, W);
  k_cvt<<<2048, 256, 0, stream>>>(x, Xb);
  const int ngemm = (8192 / 256) * (4096 / 256);   // 512
  k_gemm<<<ngemm, 512, 0, stream>>>(Xb, W, bias, y);
}